// Round 3
// baseline (367.174 us; speedup 1.0000x reference)
//
#include <hip/hip_runtime.h>

// TreeLSTM cell: one bf16-MFMA GEMM [131072,512]x[512,1024] + gated epilogue.
// Main kernel v3: 256-row x 64-hcol blocks, 8 waves (4M x 2N), acc[mi][seg] so the
// epilogue is lane-local. A: 3-deep LDS ring staged 2 tiles ahead via global_load_lds
// (XOR-swizzled via pre-swizzled global source, rule #21). B: pre-transposed into
// MFMA fragment order (prep_w_frag) -> per-fragment loads are fully coalesced global
// reads, L2-resident, no LDS and no barriers for B. One raw s_barrier + vmcnt drain
// per K-tile; iteration length (~2000cy MFMA) >> HBM latency, so drain doesn't stall.

typedef unsigned short u16;
typedef unsigned int u32;
typedef __bf16 bf16x8 __attribute__((ext_vector_type(8)));
typedef float f32x16 __attribute__((ext_vector_type(16)));
typedef u16 u16x4 __attribute__((ext_vector_type(4)));
typedef u16 u16x8 __attribute__((ext_vector_type(8)));

#define NTOT 131072
#define NHOFF ((size_t)131072 * 256)

__device__ __forceinline__ u16 f2bf(float f) {
  u32 u = __float_as_uint(f);
  return (u16)((u + 0x7FFFu + ((u >> 16) & 1u)) >> 16);  // RNE
}

// ---- B in fragment order: [g(4)][kt(8)][ksub(4)][hi(2)][np(256)][8 bf16] ----
// np = nf*64 + wn*32 + lr  ->  pre-col j = nf*256 + g*64 + wn*32 + lr  (seg nf).
__global__ void prep_w_frag(const float* __restrict__ Wiou, const float* __restrict__ Uiou,
                            const float* __restrict__ Wf, const float* __restrict__ Uf,
                            u16* __restrict__ BpackF) {
  int c = blockIdx.x * 256 + threadIdx.x;  // 65536 chunks of 8 k-elems
  int np = c & 255;
  int r = c >> 8;
  int hi = r & 1; r >>= 1;
  int ks = r & 3; r >>= 2;
  int kt = r & 7; r >>= 3;
  int g  = r & 3;
  int j = (np >> 6) * 256 + g * 64 + (np & 63);
  int k0 = kt * 64 + ks * 16 + hi * 8;
  const float* src;
  if (j < 768) src = (k0 < 256) ? (Wiou + (size_t)j * 256 + k0) : (Uiou + (size_t)j * 256 + (k0 - 256));
  else { int jj = j - 768; src = (k0 < 256) ? (Wf + (size_t)jj * 256 + k0) : (Uf + (size_t)jj * 256 + (k0 - 256)); }
  float4 f0 = *(const float4*)(src);
  float4 f1 = *(const float4*)(src + 4);
  u16x8 v;
  v[0] = f2bf(f0.x); v[1] = f2bf(f0.y); v[2] = f2bf(f0.z); v[3] = f2bf(f0.w);
  v[4] = f2bf(f1.x); v[5] = f2bf(f1.y); v[6] = f2bf(f1.z); v[7] = f2bf(f1.w);
  *(u16x8*)(BpackF + (size_t)c * 8) = v;
}

// ---- legacy B layout (fallback path only) ----
__global__ void prep_w_legacy(const float* __restrict__ Wiou, const float* __restrict__ Uiou,
                              const float* __restrict__ Wf, const float* __restrict__ Uf,
                              u16* __restrict__ Bpack) {
  int cid = blockIdx.x * 256 + threadIdx.x;
  int j = cid >> 6;
  int kc = cid & 63;
  int k = kc * 8;
  int kt = kc >> 3, k8 = kc & 7;
  int s = j >> 8, g = (j >> 6) & 3, e = j & 63;
  int c = s * 64 + e;
  const float* src;
  if (j < 768) src = (k < 256) ? (Wiou + j * 256 + k) : (Uiou + j * 256 + (k - 256));
  else { int jj = j - 768; src = (k < 256) ? (Wf + jj * 256 + k) : (Uf + jj * 256 + (k - 256)); }
  float4 f0 = *(const float4*)(src);
  float4 f1 = *(const float4*)(src + 4);
  u16x8 v;
  v[0] = f2bf(f0.x); v[1] = f2bf(f0.y); v[2] = f2bf(f0.z); v[3] = f2bf(f0.w);
  v[4] = f2bf(f1.x); v[5] = f2bf(f1.y); v[6] = f2bf(f1.z); v[7] = f2bf(f1.w);
  int slot = (g * 8 + kt) * 2048 + ((c * 8 + k8) ^ (c & 7));
  *(u16x8*)(Bpack + slot * 8) = v;
}

__global__ void prep_bias(const float* __restrict__ biou, const float* __restrict__ wfb,
                          const float* __restrict__ ufb, const float* __restrict__ bfv,
                          float* __restrict__ Bias) {
  int j = blockIdx.x * 256 + threadIdx.x;  // 1024 exact
  Bias[j] = (j < 768) ? biou[j] : (wfb[j - 768] + ufb[j - 768] + bfv[j - 768]);
}

// Apack[n] = [ x[n] (512B bf16) | child_h[idx[n]] (512B bf16) ], row-major.
__global__ void prep_apack(const float* __restrict__ x, const float* __restrict__ ch,
                           const int* __restrict__ cidx, u16* __restrict__ Apack) {
  int e = blockIdx.x * 256 + threadIdx.x;  // 131072 rows x 64 chunks of 8
  int n = e >> 6, c = e & 63;
  const float* src = (c < 32) ? (x + (size_t)n * 256 + c * 8)
                              : (ch + (size_t)cidx[n] * 256 + (c - 32) * 8);
  float4 f0 = *(const float4*)src;
  float4 f1 = *(const float4*)(src + 4);
  u16x8 v;
  v[0] = f2bf(f0.x); v[1] = f2bf(f0.y); v[2] = f2bf(f0.z); v[3] = f2bf(f0.w);
  v[4] = f2bf(f1.x); v[5] = f2bf(f1.y); v[6] = f2bf(f1.z); v[7] = f2bf(f1.w);
  *(u16x8*)(Apack + (size_t)n * 512 + c * 8) = v;
}

// -------------------- pipelined main --------------------
__global__ __launch_bounds__(512, 2)
void treelstm_main8(const u16* __restrict__ Apack, const u16* __restrict__ BpackF,
                    const float* __restrict__ Bias, const float* __restrict__ child_c,
                    const int* __restrict__ cidx, float* __restrict__ out) {
  __shared__ __align__(16) u16 ring[3 * 16384];   // 3 x 32KB A-tiles (256 rows x 64 k)
  __shared__ int lds_cidx[256];

  const int tid = threadIdx.x;
  const int n0 = blockIdx.x * 256;
  const int g = blockIdx.y;
  if (tid < 256) lds_cidx[tid] = cidx[n0 + tid];   // visibility via loop barrier 0

  const int lane = tid & 63, w = tid >> 6;
  const int wm = w >> 1, wn = w & 1;               // wave tile: 64 rows x (4 segs x 32 hcols)
  const int lr = lane & 31, hi = lane >> 5;

  // A staging: per-lane global source, inverse-swizzled (rule #21); LDS dest linear.
  const u16* aSrc = Apack + (size_t)(n0 + (tid >> 3)) * 512
                    + (((tid & 7) ^ ((tid >> 3) & 7)) << 3);
  // B fragments: per-lane coalesced source in fragment order.
  const u16* bP = BpackF + (size_t)g * 131072 + (size_t)hi * 2048 + (size_t)(wn * 32 + lr) * 8;

  u16* bufs[3] = {ring, ring + 16384, ring + 32768};

  // A read offsets (bytes within a buffer)
  int arowb[2];
  #pragma unroll
  for (int mi = 0; mi < 2; mi++) arowb[mi] = (wm * 64 + mi * 32 + lr) * 128;
  const int aswz = (lr & 7) << 4;
  const int hib = hi * 16;

  f32x16 acc[2][4] = {};   // [mi][seg]

  #define STAGE(T, BUF)                                                              \
    { _Pragma("unroll") for (int q = 0; q < 4; ++q)                                  \
        __builtin_amdgcn_global_load_lds(                                            \
            (const __attribute__((address_space(1))) void*)(aSrc + (T) * 64 + q * 32768), \
            (__attribute__((address_space(3))) void*)((BUF) + q * 4096 + w * 512),   \
            16, 0, 0); }

  STAGE(0, bufs[0]);
  STAGE(1, bufs[1]);

  #pragma unroll
  for (int t = 0; t < 8; ++t) {
    __builtin_amdgcn_sched_barrier(0);
    asm volatile("s_waitcnt vmcnt(0) lgkmcnt(0)\n\ts_barrier" ::: "memory");
    __builtin_amdgcn_sched_barrier(0);
    if (t < 6) STAGE(t + 2, bufs[(t + 2) % 3]);
    // B fragment loads: 16 coalesced global_load_dwordx4 (L2-resident weights)
    bf16x8 bfr[4][4];
    #pragma unroll
    for (int nf = 0; nf < 4; ++nf)
      #pragma unroll
      for (int ks = 0; ks < 4; ++ks)
        bfr[nf][ks] = *(const bf16x8*)(bP + (size_t)t * 16384 + ks * 4096 + nf * 512);
    // A fragment reads from LDS ring (swizzled)
    const char* cur = (const char*)bufs[t % 3];
    bf16x8 afr[2][4];
    #pragma unroll
    for (int mi = 0; mi < 2; ++mi)
      #pragma unroll
      for (int ks = 0; ks < 4; ++ks)
        afr[mi][ks] = *(const bf16x8*)(cur + arowb[mi] + ((ks * 32 + hib) ^ aswz));
    __builtin_amdgcn_s_setprio(1);
    #pragma unroll
    for (int ks = 0; ks < 4; ++ks)
      #pragma unroll
      for (int mi = 0; mi < 2; ++mi)
        #pragma unroll
        for (int nf = 0; nf < 4; ++nf)
          acc[mi][nf] = __builtin_amdgcn_mfma_f32_32x32x16_bf16(afr[mi][ks], bfr[nf][ks],
                                                                acc[mi][nf], 0, 0, 0);
    __builtin_amdgcn_s_setprio(0);
  }
  #undef STAGE

  // ---- epilogue: i,o,u,f are acc[mi][0..3][reg] in the SAME lane ----
  const int hcol = g * 64 + wn * 32 + lr;
  float b4[4];
  #pragma unroll
  for (int nf = 0; nf < 4; ++nf) b4[nf] = Bias[nf * 256 + hcol];
  #pragma unroll
  for (int mi = 0; mi < 2; ++mi) {
    #pragma unroll
    for (int reg = 0; reg < 16; ++reg) {
      int rowb = wm * 64 + mi * 32 + (reg & 3) + 8 * (reg >> 2) + 4 * hi;  // C/D map
      size_t n = (size_t)(n0 + rowb);
      float i_ = acc[mi][0][reg] + b4[0];
      float o_ = acc[mi][1][reg] + b4[1];
      float u_ = acc[mi][2][reg] + b4[2];
      float fp = acc[mi][3][reg] + b4[3];
      float ccv = child_c[(size_t)lds_cidx[rowb] * 256 + hcol];
      float sigi = 1.f / (1.f + __expf(-i_));
      float sigo = 1.f / (1.f + __expf(-o_));
      float sigf = 1.f / (1.f + __expf(-fp));
      float tu = 2.f / (1.f + __expf(-2.f * u_)) - 1.f;
      float c = sigi * tu + sigf * ccv;
      float tc = 2.f / (1.f + __expf(-2.f * c)) - 1.f;
      out[n * 256 + hcol] = sigo * tc;
      out[NHOFF + n * 256 + hcol] = c;
    }
  }
}

// ---------- fallback main (round-1 proven path, used if ws too small) ----------
__global__ __launch_bounds__(256, 2)
void treelstm_main_f32(const float* __restrict__ x, const float* __restrict__ child_h,
                       const float* __restrict__ child_c, const int* __restrict__ cidx,
                       const u16* __restrict__ Bpack, const float* __restrict__ Bias,
                       float* __restrict__ out) {
  __shared__ __align__(16) u16 ldsA[128 * 64];
  __shared__ __align__(16) u16 ldsB[256 * 64];
  __shared__ int lds_cidx[128];

  const int tid = threadIdx.x;
  const int n0 = blockIdx.x * 128;
  const int g = blockIdx.y;

  if (tid < 128) lds_cidx[tid] = cidx[n0 + tid];

  const int lane = tid & 63, w = tid >> 6;
  const int wm = w >> 1, wn = w & 1;
  const int lr = lane & 31, hi = lane >> 5;

  f32x16 acc[2][4] = {};

  const char* ldsAb = (const char*)ldsA;
  const char* ldsBb = (const char*)ldsB;
  int arow[2];
  #pragma unroll
  for (int mi = 0; mi < 2; mi++) arow[mi] = (wm * 64 + mi * 32 + lr) * 128;
  const int aswz = (lr & 7) << 4;
  int brow[4];
  #pragma unroll
  for (int s = 0; s < 4; s++) brow[s] = (s * 64 + wn * 32 + lr) * 128;
  const int bswz = (lr & 7) << 4;

  for (int kt = 0; kt < 8; ++kt) {
    #pragma unroll
    for (int q = 0; q < 8; ++q) {
      int v = q * 256 + tid;
      int r = v >> 4;
      int kq = (v & 15) * 4;
      const float* src = (kt < 4) ? (x + (size_t)(n0 + r) * 256 + kt * 64 + kq)
                                  : (child_h + (size_t)lds_cidx[r] * 256 + (kt - 4) * 64 + kq);
      float4 d = *(const float4*)src;
      u16x4 b;
      b[0] = f2bf(d.x); b[1] = f2bf(d.y); b[2] = f2bf(d.z); b[3] = f2bf(d.w);
      int addr = (r * 128 + kq * 2) ^ ((r & 7) << 4);
      *(u16x4*)((char*)ldsA + addr) = b;
    }
    const u16* bsrc = Bpack + (g * 8 + kt) * 16384;
    #pragma unroll
    for (int q = 0; q < 8; ++q) {
      int m = q * 256 + tid;
      *(u16x8*)((char*)ldsB + m * 16) = *(const u16x8*)(bsrc + m * 8);
    }
    __syncthreads();
    #pragma unroll
    for (int ks = 0; ks < 4; ++ks) {
      int kb = ks * 32 + hi * 16;
      bf16x8 af[2], bfr[4];
      #pragma unroll
      for (int mi = 0; mi < 2; mi++)
        af[mi] = *(const bf16x8*)(ldsAb + ((arow[mi] + kb) ^ aswz));
      #pragma unroll
      for (int s = 0; s < 4; s++)
        bfr[s] = *(const bf16x8*)(ldsBb + ((brow[s] + kb) ^ bswz));
      #pragma unroll
      for (int mi = 0; mi < 2; mi++)
        #pragma unroll
        for (int s = 0; s < 4; s++)
          acc[mi][s] = __builtin_amdgcn_mfma_f32_32x32x16_bf16(af[mi], bfr[s], acc[mi][s], 0, 0, 0);
    }
    __syncthreads();
  }

  const int tcol = g * 64 + wn * 32 + lr;
  const float bi = Bias[tcol], bo = Bias[256 + tcol], bu = Bias[512 + tcol], bfg = Bias[768 + tcol];
  #pragma unroll
  for (int mi = 0; mi < 2; mi++) {
    #pragma unroll
    for (int reg = 0; reg < 16; ++reg) {
      int row = wm * 64 + mi * 32 + (reg & 3) + 8 * (reg >> 2) + 4 * hi;
      int n = n0 + row;
      float i_ = acc[mi][0][reg] + bi;
      float o_ = acc[mi][1][reg] + bo;
      float u_ = acc[mi][2][reg] + bu;
      float fp = acc[mi][3][reg] + bfg;
      float ccv = child_c[(size_t)lds_cidx[row] * 256 + tcol];
      float sigi = 1.f / (1.f + __expf(-i_));
      float sigo = 1.f / (1.f + __expf(-o_));
      float sigf = 1.f / (1.f + __expf(-fp));
      float tu = 2.f / (1.f + __expf(-2.f * u_)) - 1.f;
      float c = sigi * tu + sigf * ccv;
      float tc = 2.f / (1.f + __expf(-2.f * c)) - 1.f;
      out[(size_t)n * 256 + tcol] = sigo * tc;
      out[NHOFF + (size_t)n * 256 + tcol] = c;
    }
  }
}

extern "C" void kernel_launch(void* const* d_in, const int* in_sizes, int n_in,
                              void* d_out, int out_size, void* d_ws, size_t ws_size,
                              hipStream_t stream) {
  const float* x    = (const float*)d_in[0];
  const float* ch   = (const float*)d_in[1];
  const float* cc   = (const float*)d_in[2];
  const int*   ci   = (const int*)d_in[3];
  const float* Wiou = (const float*)d_in[4];
  const float* Uiou = (const float*)d_in[5];
  const float* biou = (const float*)d_in[6];
  const float* Wf   = (const float*)d_in[7];
  const float* Wfb  = (const float*)d_in[8];
  const float* Uf   = (const float*)d_in[9];
  const float* Ufb  = (const float*)d_in[10];
  const float* bfv  = (const float*)d_in[11];

  u16* Bpack = (u16*)d_ws;                              // 1 MB bf16 packed weights
  float* Bias = (float*)((char*)d_ws + (1 << 20));      // 4 KB combined bias
  u16* Apack = (u16*)((char*)d_ws + (2 << 20));         // 134.2 MB packed [x|hc] bf16

  const size_t need = (size_t)(2 << 20) + (size_t)NTOT * 512 * sizeof(u16);

  prep_bias<<<4, 256, 0, stream>>>(biou, Wfb, Ufb, bfv, Bias);

  if (ws_size >= need) {
    prep_w_frag<<<256, 256, 0, stream>>>(Wiou, Uiou, Wf, Uf, Bpack);
    prep_apack<<<32768, 256, 0, stream>>>(x, ch, ci, Apack);
    dim3 grid(512, 4);
    treelstm_main8<<<grid, 512, 0, stream>>>(Apack, Bpack, Bias, cc, ci, (float*)d_out);
  } else {
    prep_w_legacy<<<256, 256, 0, stream>>>(Wiou, Uiou, Wf, Uf, Bpack);
    dim3 grid(1024, 4);
    treelstm_main_f32<<<grid, 256, 0, stream>>>(x, ch, cc, ci, Bpack, Bias, (float*)d_out);
  }
}

// Round 4
// 326.214 us; speedup vs baseline: 1.1256x; 1.1256x over previous
//
#include <hip/hip_runtime.h>

// TreeLSTM cell: one bf16-MFMA GEMM [131072,512]x[512,1024] + gated epilogue.
// v4: 256-row x (4seg x 64hcol) blocks, 8 waves (4M x 2N), acc[mi][seg] -> lane-local
// epilogue. A and B both double-buffered in LDS (128KB), staged via global_load_lds
// width=16 (linear dest; XOR swizzle carried on the pre-swizzled global source, rule #21).
// Counted-vmcnt pipeline: STAGE depth 2, vmcnt(8) at iter top (never 0 mid-loop),
// 2 sub-phases per K-tile {12 ds_read -> lgkm(0) -> 16 MFMA}, reads-done barrier before
// the STAGE overwrite, setprio(1) around MFMA clusters. XCD-chunked block swizzle.

typedef unsigned short u16;
typedef unsigned int u32;
typedef __bf16 bf16x8 __attribute__((ext_vector_type(8)));
typedef float f32x16 __attribute__((ext_vector_type(16)));
typedef u16 u16x4 __attribute__((ext_vector_type(4)));
typedef u16 u16x8 __attribute__((ext_vector_type(8)));

#define NTOT 131072
#define NHOFF ((size_t)131072 * 256)
#define AS1 __attribute__((address_space(1)))
#define AS3 __attribute__((address_space(3)))

__device__ __forceinline__ u16 f2bf(float f) {
  u32 u = __float_as_uint(f);
  return (u16)((u + 0x7FFFu + ((u >> 16) & 1u)) >> 16);  // RNE
}

// Pack Wcat[1024][512] -> bf16 per (g, kt) tiles of 256 pcols x 64 k, stored as the
// exact swizzled LDS image: slot = (c*8 + k8) ^ (c&7) (16B slots), c = seg*64 + e.
__global__ void prep_w(const float* __restrict__ Wiou, const float* __restrict__ Uiou,
                       const float* __restrict__ Wf, const float* __restrict__ Uf,
                       u16* __restrict__ Bpack) {
  int cid = blockIdx.x * 256 + threadIdx.x;  // 65536 chunks of 8
  int j = cid >> 6;
  int kc = cid & 63;
  int k = kc * 8;
  int kt = kc >> 3, k8 = kc & 7;
  int s = j >> 8, g = (j >> 6) & 3, e = j & 63;
  int c = s * 64 + e;
  const float* src;
  if (j < 768) src = (k < 256) ? (Wiou + j * 256 + k) : (Uiou + j * 256 + (k - 256));
  else { int jj = j - 768; src = (k < 256) ? (Wf + jj * 256 + k) : (Uf + jj * 256 + (k - 256)); }
  float4 f0 = *(const float4*)(src);
  float4 f1 = *(const float4*)(src + 4);
  u16x8 v;
  v[0] = f2bf(f0.x); v[1] = f2bf(f0.y); v[2] = f2bf(f0.z); v[3] = f2bf(f0.w);
  v[4] = f2bf(f1.x); v[5] = f2bf(f1.y); v[6] = f2bf(f1.z); v[7] = f2bf(f1.w);
  int slot = (g * 8 + kt) * 2048 + ((c * 8 + k8) ^ (c & 7));
  *(u16x8*)(Bpack + slot * 8) = v;
}

__global__ void prep_bias(const float* __restrict__ biou, const float* __restrict__ wfb,
                          const float* __restrict__ ufb, const float* __restrict__ bfv,
                          float* __restrict__ Bias) {
  int j = blockIdx.x * 256 + threadIdx.x;  // 1024 exact
  Bias[j] = (j < 768) ? biou[j] : (wfb[j - 768] + ufb[j - 768] + bfv[j - 768]);
}

// Apack[n] = [ x[n] (512B bf16) | child_h[idx[n]] (512B bf16) ], row-major.
__global__ void prep_apack(const float* __restrict__ x, const float* __restrict__ ch,
                           const int* __restrict__ cidx, u16* __restrict__ Apack) {
  int e = blockIdx.x * 256 + threadIdx.x;  // 131072 rows x 64 chunks of 8
  int n = e >> 6, c = e & 63;
  const float* src = (c < 32) ? (x + (size_t)n * 256 + c * 8)
                              : (ch + (size_t)cidx[n] * 256 + (c - 32) * 8);
  float4 f0 = *(const float4*)src;
  float4 f1 = *(const float4*)(src + 4);
  u16x8 v;
  v[0] = f2bf(f0.x); v[1] = f2bf(f0.y); v[2] = f2bf(f0.z); v[3] = f2bf(f0.w);
  v[4] = f2bf(f1.x); v[5] = f2bf(f1.y); v[6] = f2bf(f1.z); v[7] = f2bf(f1.w);
  *(u16x8*)(Apack + (size_t)n * 512 + c * 8) = v;
}

// -------------------- counted-vmcnt pipelined main --------------------
__global__ __launch_bounds__(512, 2)
void treelstm_main_v4(const u16* __restrict__ Apack, const u16* __restrict__ Bpack,
                      const float* __restrict__ Bias, const float* __restrict__ child_c,
                      const int* __restrict__ cidx, float* __restrict__ out) {
  // A dbuf: 2 x 32KB (256 rows x 64k), B dbuf: 2 x 32KB (256 pcols x 64k)
  __shared__ __align__(16) u16 lds[4 * 16384];   // [A0|A1|B0|B1]
  __shared__ int lds_cidx[256];

  const int tid = threadIdx.x;
  // XCD-chunked bijective swizzle (2048 % 8 == 0); g-major-inner -> 4 sibling g-blocks
  // sharing one A-tile land adjacent on the same XCD (L2 reuse of A and child_c rows).
  const int orig = blockIdx.x;
  const int bid = (orig & 7) * 256 + (orig >> 3);
  const int g = bid & 3;
  const int n0 = (bid >> 2) * 256;

  if (tid < 256) lds_cidx[tid] = cidx[n0 + tid];

  const int lane = tid & 63, w = tid >> 6;
  const int wm = w >> 1, wn = w & 1;   // wave tile: 64 rows x (4 segs x 32 hcols)
  const int lr = lane & 31, hi = lane >> 5;

  // A staging source: per-lane, inverse-swizzled (rule #21); LDS dest linear.
  const u16* aSrc = Apack + (size_t)(n0 + (tid >> 3)) * 512
                    + (((tid & 7) ^ ((tid >> 3) & 7)) << 3);
  // B staging source: pre-swizzled image, fully linear copy.
  const u16* bSrc = Bpack + (size_t)(g * 8) * 16384 + (size_t)tid * 8;

  u16* ldsA[2] = {lds, lds + 16384};
  u16* ldsB[2] = {lds + 32768, lds + 49152};

  int arowb[2];
  #pragma unroll
  for (int mi = 0; mi < 2; mi++) arowb[mi] = (wm * 64 + mi * 32 + lr) * 128;
  int brow[4];
  #pragma unroll
  for (int s = 0; s < 4; s++) brow[s] = (s * 64 + wn * 32 + lr) * 128;
  const int swz = (lr & 7) << 4;
  const int hib = hi * 16;

  f32x16 acc[2][4] = {};   // [mi][seg]

  // 8 loads per STAGE (4 A + 4 B), each 512thr x 16B = 8KB
  #define STAGE(T, ab, bb)                                                             \
    { _Pragma("unroll") for (int q = 0; q < 4; ++q)                                    \
        __builtin_amdgcn_global_load_lds(                                              \
            (const AS1 void*)(aSrc + (T) * 64 + q * 32768),                            \
            (AS3 void*)((ab) + q * 4096 + w * 512), 16, 0, 0);                         \
      _Pragma("unroll") for (int q = 0; q < 4; ++q)                                    \
        __builtin_amdgcn_global_load_lds(                                              \
            (const AS1 void*)(bSrc + (size_t)(T) * 16384 + q * 4096),                  \
            (AS3 void*)((bb) + q * 4096 + w * 512), 16, 0, 0); }

  STAGE(0, ldsA[0], ldsB[0]);
  STAGE(1, ldsA[1], ldsB[1]);

  #pragma unroll
  for (int t = 0; t < 8; ++t) {
    // wait for STAGE(t) (newest 8 outstanding = STAGE(t+1)); never drain to 0 mid-loop
    if (t < 7) asm volatile("s_waitcnt vmcnt(8)" ::: "memory");
    else       asm volatile("s_waitcnt vmcnt(0)" ::: "memory");
    __builtin_amdgcn_s_barrier();          // buf[t&1] ready for all waves

    const char* bufA = (const char*)ldsA[t & 1];
    const char* bufB = (const char*)ldsB[t & 1];

    // ---- phase 1: ks = 0,1 ----
    bf16x8 a0[2][2], b0[4][2];
    #pragma unroll
    for (int kk = 0; kk < 2; ++kk) {
      #pragma unroll
      for (int mi = 0; mi < 2; ++mi)
        a0[mi][kk] = *(const bf16x8*)(bufA + arowb[mi] + ((kk * 32 + hib) ^ swz));
      #pragma unroll
      for (int nf = 0; nf < 4; ++nf)
        b0[nf][kk] = *(const bf16x8*)(bufB + brow[nf] + ((kk * 32 + hib) ^ swz));
    }
    asm volatile("s_waitcnt lgkmcnt(0)" ::: "memory");
    __builtin_amdgcn_s_setprio(1);
    #pragma unroll
    for (int kk = 0; kk < 2; ++kk)
      #pragma unroll
      for (int mi = 0; mi < 2; ++mi)
        #pragma unroll
        for (int nf = 0; nf < 4; ++nf)
          acc[mi][nf] = __builtin_amdgcn_mfma_f32_32x32x16_bf16(a0[mi][kk], b0[nf][kk],
                                                                acc[mi][nf], 0, 0, 0);
    __builtin_amdgcn_s_setprio(0);

    // ---- phase 2: ks = 2,3 ----
    bf16x8 a1[2][2], b1[4][2];
    #pragma unroll
    for (int kk = 0; kk < 2; ++kk) {
      #pragma unroll
      for (int mi = 0; mi < 2; ++mi)
        a1[mi][kk] = *(const bf16x8*)(bufA + arowb[mi] + (((kk + 2) * 32 + hib) ^ swz));
      #pragma unroll
      for (int nf = 0; nf < 4; ++nf)
        b1[nf][kk] = *(const bf16x8*)(bufB + brow[nf] + (((kk + 2) * 32 + hib) ^ swz));
    }
    asm volatile("s_waitcnt lgkmcnt(0)" ::: "memory");
    __builtin_amdgcn_s_barrier();          // ALL waves done reading buf[t&1]
    if (t < 6) STAGE(t + 2, ldsA[t & 1], ldsB[t & 1]);   // overwrite just-freed buffer
    __builtin_amdgcn_s_setprio(1);
    #pragma unroll
    for (int kk = 0; kk < 2; ++kk)
      #pragma unroll
      for (int mi = 0; mi < 2; ++mi)
        #pragma unroll
        for (int nf = 0; nf < 4; ++nf)
          acc[mi][nf] = __builtin_amdgcn_mfma_f32_32x32x16_bf16(a1[mi][kk], b1[nf][kk],
                                                                acc[mi][nf], 0, 0, 0);
    __builtin_amdgcn_s_setprio(0);
  }
  #undef STAGE

  // ---- epilogue: i,o,u,f are acc[mi][0..3][reg] in the SAME lane ----
  const int hcol = g * 64 + wn * 32 + lr;
  float b4[4];
  #pragma unroll
  for (int nf = 0; nf < 4; ++nf) b4[nf] = Bias[nf * 256 + hcol];
  #pragma unroll
  for (int mi = 0; mi < 2; ++mi) {
    #pragma unroll
    for (int reg = 0; reg < 16; ++reg) {
      int rowb = wm * 64 + mi * 32 + (reg & 3) + 8 * (reg >> 2) + 4 * hi;  // C/D map
      size_t n = (size_t)(n0 + rowb);
      float i_ = acc[mi][0][reg] + b4[0];
      float o_ = acc[mi][1][reg] + b4[1];
      float u_ = acc[mi][2][reg] + b4[2];
      float fp = acc[mi][3][reg] + b4[3];
      float ccv = child_c[(size_t)lds_cidx[rowb] * 256 + hcol];
      float sigi = 1.f / (1.f + __expf(-i_));
      float sigo = 1.f / (1.f + __expf(-o_));
      float sigf = 1.f / (1.f + __expf(-fp));
      float tu = 2.f / (1.f + __expf(-2.f * u_)) - 1.f;
      float c = sigi * tu + sigf * ccv;
      float tc = 2.f / (1.f + __expf(-2.f * c)) - 1.f;
      out[n * 256 + hcol] = sigo * tc;
      out[NHOFF + n * 256 + hcol] = c;
    }
  }
}

// ---------- fallback main (round-1 proven path, used if ws too small) ----------
__global__ __launch_bounds__(256, 2)
void treelstm_main_f32(const float* __restrict__ x, const float* __restrict__ child_h,
                       const float* __restrict__ child_c, const int* __restrict__ cidx,
                       const u16* __restrict__ Bpack, const float* __restrict__ Bias,
                       float* __restrict__ out) {
  __shared__ __align__(16) u16 ldsA[128 * 64];
  __shared__ __align__(16) u16 ldsB[256 * 64];
  __shared__ int lds_cidx[128];

  const int tid = threadIdx.x;
  const int n0 = blockIdx.x * 128;
  const int g = blockIdx.y;

  if (tid < 128) lds_cidx[tid] = cidx[n0 + tid];

  const int lane = tid & 63, w = tid >> 6;
  const int wm = w >> 1, wn = w & 1;
  const int lr = lane & 31, hi = lane >> 5;

  f32x16 acc[2][4] = {};

  const char* ldsAb = (const char*)ldsA;
  const char* ldsBb = (const char*)ldsB;
  int arow[2];
  #pragma unroll
  for (int mi = 0; mi < 2; mi++) arow[mi] = (wm * 64 + mi * 32 + lr) * 128;
  const int aswz = (lr & 7) << 4;
  int brow[4];
  #pragma unroll
  for (int s = 0; s < 4; s++) brow[s] = (s * 64 + wn * 32 + lr) * 128;
  const int bswz = (lr & 7) << 4;

  for (int kt = 0; kt < 8; ++kt) {
    #pragma unroll
    for (int q = 0; q < 8; ++q) {
      int v = q * 256 + tid;
      int r = v >> 4;
      int kq = (v & 15) * 4;
      const float* src = (kt < 4) ? (x + (size_t)(n0 + r) * 256 + kt * 64 + kq)
                                  : (child_h + (size_t)lds_cidx[r] * 256 + (kt - 4) * 64 + kq);
      float4 d = *(const float4*)src;
      u16x4 b;
      b[0] = f2bf(d.x); b[1] = f2bf(d.y); b[2] = f2bf(d.z); b[3] = f2bf(d.w);
      int addr = (r * 128 + kq * 2) ^ ((r & 7) << 4);
      *(u16x4*)((char*)ldsA + addr) = b;
    }
    const u16* bsrc = Bpack + (g * 8 + kt) * 16384;
    #pragma unroll
    for (int q = 0; q < 8; ++q) {
      int m = q * 256 + tid;
      *(u16x8*)((char*)ldsB + m * 16) = *(const u16x8*)(bsrc + m * 8);
    }
    __syncthreads();
    #pragma unroll
    for (int ks = 0; ks < 4; ++ks) {
      int kb = ks * 32 + hi * 16;
      bf16x8 af[2], bfr[4];
      #pragma unroll
      for (int mi = 0; mi < 2; mi++)
        af[mi] = *(const bf16x8*)(ldsAb + ((arow[mi] + kb) ^ aswz));
      #pragma unroll
      for (int s = 0; s < 4; s++)
        bfr[s] = *(const bf16x8*)(ldsBb + ((brow[s] + kb) ^ bswz));
      #pragma unroll
      for (int mi = 0; mi < 2; mi++)
        #pragma unroll
        for (int s = 0; s < 4; s++)
          acc[mi][s] = __builtin_amdgcn_mfma_f32_32x32x16_bf16(af[mi], bfr[s], acc[mi][s], 0, 0, 0);
    }
    __syncthreads();
  }

  const int tcol = g * 64 + wn * 32 + lr;
  const float bi = Bias[tcol], bo = Bias[256 + tcol], bu = Bias[512 + tcol], bfg = Bias[768 + tcol];
  #pragma unroll
  for (int mi = 0; mi < 2; mi++) {
    #pragma unroll
    for (int reg = 0; reg < 16; ++reg) {
      int row = wm * 64 + mi * 32 + (reg & 3) + 8 * (reg >> 2) + 4 * hi;
      int n = n0 + row;
      float i_ = acc[mi][0][reg] + bi;
      float o_ = acc[mi][1][reg] + bo;
      float u_ = acc[mi][2][reg] + bu;
      float fp = acc[mi][3][reg] + bfg;
      float ccv = child_c[(size_t)lds_cidx[row] * 256 + tcol];
      float sigi = 1.f / (1.f + __expf(-i_));
      float sigo = 1.f / (1.f + __expf(-o_));
      float sigf = 1.f / (1.f + __expf(-fp));
      float tu = 2.f / (1.f + __expf(-2.f * u_)) - 1.f;
      float c = sigi * tu + sigf * ccv;
      float tc = 2.f / (1.f + __expf(-2.f * c)) - 1.f;
      out[(size_t)n * 256 + tcol] = sigo * tc;
      out[NHOFF + (size_t)n * 256 + tcol] = c;
    }
  }
}

extern "C" void kernel_launch(void* const* d_in, const int* in_sizes, int n_in,
                              void* d_out, int out_size, void* d_ws, size_t ws_size,
                              hipStream_t stream) {
  const float* x    = (const float*)d_in[0];
  const float* ch   = (const float*)d_in[1];
  const float* cc   = (const float*)d_in[2];
  const int*   ci   = (const int*)d_in[3];
  const float* Wiou = (const float*)d_in[4];
  const float* Uiou = (const float*)d_in[5];
  const float* biou = (const float*)d_in[6];
  const float* Wf   = (const float*)d_in[7];
  const float* Wfb  = (const float*)d_in[8];
  const float* Uf   = (const float*)d_in[9];
  const float* Ufb  = (const float*)d_in[10];
  const float* bfv  = (const float*)d_in[11];

  u16* Bpack = (u16*)d_ws;                              // 1 MB bf16 packed weights
  float* Bias = (float*)((char*)d_ws + (1 << 20));      // 4 KB combined bias
  u16* Apack = (u16*)((char*)d_ws + (2 << 20));         // 134.2 MB packed [x|hc] bf16

  const size_t need = (size_t)(2 << 20) + (size_t)NTOT * 512 * sizeof(u16);

  prep_w<<<256, 256, 0, stream>>>(Wiou, Uiou, Wf, Uf, Bpack);
  prep_bias<<<4, 256, 0, stream>>>(biou, Wfb, Ufb, bfv, Bias);

  if (ws_size >= need) {
    prep_apack<<<32768, 256, 0, stream>>>(x, ch, ci, Apack);
    treelstm_main_v4<<<2048, 512, 0, stream>>>(Apack, Bpack, Bias, cc, ci, (float*)d_out);
  } else {
    dim3 grid(1024, 4);
    treelstm_main_f32<<<grid, 256, 0, stream>>>(x, ch, cc, ci, Bpack, Bias, (float*)d_out);
  }
}